// Round 4
// baseline (238.696 us; speedup 1.0000x reference)
//
#include <hip/hip_runtime.h>

#define N_PTS 8192
#define D_DIM 256
#define BN 256              // set1 rows per block
#define BM 128              // set2 rows per block
#define BK 64
#define NBLK ((N_PTS / BN) * (N_PTS / BM))   // 32*64 = 2048
#define INF_BITS 0x7F800000u

typedef __attribute__((ext_vector_type(8))) short short8;
typedef __attribute__((ext_vector_type(4))) float f32x4;

// async global->LDS, 16B/lane; LDS dest = wave-uniform base + lane*16
__device__ __forceinline__ void gload_lds16(const ushort* g, ushort* l) {
    __builtin_amdgcn_global_load_lds(
        (const __attribute__((address_space(1))) void*)g,
        (__attribute__((address_space(3))) void*)l, 16, 0, 0);
}

__device__ __forceinline__ ushort f2bf(float x) {
    unsigned u = __float_as_uint(x);
    return (ushort)((u + 0x7FFFu + ((u >> 16) & 1u)) >> 16);  // RNE, no NaNs here
}

// ---- fused prep: bf16 convert + row sqnorms (fp32 exact) + INF init + counter=0 ----
// 2048 blocks x 256 threads; each thread converts 8 consecutive floats (= 1/32 row).
__global__ void prep_kernel(const float* __restrict__ s1, const float* __restrict__ s2,
                            ushort* __restrict__ b1, ushort* __restrict__ b2,
                            float* __restrict__ sq1, float* __restrict__ sq2,
                            unsigned* __restrict__ rowmin2, unsigned* __restrict__ colmin2,
                            unsigned* __restrict__ counter) {
    const int half = N_PTS * D_DIM;
    int t = blockIdx.x * 256 + threadIdx.x;
    int e = t * 8;
    bool first = e < half;
    const float* src = first ? s1 : s2;
    ushort* dst = first ? b1 : b2;
    int off = first ? e : e - half;
    float4 v0 = *(const float4*)(src + off);
    float4 v1 = *(const float4*)(src + off + 4);
    float s = v0.x * v0.x + v0.y * v0.y + v0.z * v0.z + v0.w * v0.w
            + v1.x * v1.x + v1.y * v1.y + v1.z * v1.z + v1.w * v1.w;
    ushort4 o0 = { f2bf(v0.x), f2bf(v0.y), f2bf(v0.z), f2bf(v0.w) };
    ushort4 o1 = { f2bf(v1.x), f2bf(v1.y), f2bf(v1.z), f2bf(v1.w) };
    *(ushort4*)(dst + off)     = o0;
    *(ushort4*)(dst + off + 4) = o1;
    // one row = 32 consecutive threads; xor masks <=16 stay inside the half-wave
    #pragma unroll
    for (int m = 1; m <= 16; m <<= 1) s += __shfl_xor(s, m, 64);
    int sub = threadIdx.x & 31;
    int row = off >> 8;
    if (sub == 0) (first ? sq1 : sq2)[row] = s;
    if (sub == 1) (first ? rowmin2 : colmin2)[row] = INF_BITS;
    if (t == 0) *counter = 0;
}

// ---- MFMA gram + fused d^2 + row/col min + last-block final reduction ----
__global__ __launch_bounds__(256, 2) void tile_kernel(
    const ushort* __restrict__ B1, const ushort* __restrict__ B2,
    const float* __restrict__ sq1, const float* __restrict__ sq2,
    unsigned* __restrict__ rowmin2, unsigned* __restrict__ colmin2,
    unsigned* __restrict__ counter, float* __restrict__ out) {
    // unpadded row-major [rows][BK] bf16, XOR-swizzled in 16B chunks:
    // LDS slot (row, sc) holds global chunk (row, sc ^ (row&7))
    __shared__ ushort As[BN * BK] __attribute__((aligned(16)));   // 32 KB
    __shared__ ushort Bs[BM * BK] __attribute__((aligned(16)));   // 16 KB
    __shared__ unsigned rs[BN];
    __shared__ unsigned cs[BM];
    __shared__ unsigned s_last;
    __shared__ float wsum[4];

    const int tid  = threadIdx.x;
    const int lane = tid & 63;
    const int w    = tid >> 6;
    const int quad = lane >> 4;
    const int c    = lane & 15;
    const int n_off = (w >> 1) * 128;   // wave tile: 128(n) x 64(m)
    const int m_off = (w & 1) * 64;
    const int n0 = blockIdx.y * BN;
    const int m0 = blockIdx.x * BM;

    rs[tid] = INF_BITS;
    if (tid < BM) cs[tid] = INF_BITS;

    f32x4 acc[8][4];
    #pragma unroll
    for (int ti = 0; ti < 8; ti++)
        #pragma unroll
        for (int tj = 0; tj < 4; tj++) acc[ti][tj] = (f32x4){0.f, 0.f, 0.f, 0.f};

    for (int k0 = 0; k0 < D_DIM; k0 += BK) {
        // stage As: 256 rows x 8 chunks = 2048 chunks, 8 rounds of 256
        #pragma unroll
        for (int r = 0; r < 8; r++) {
            int idx = r * 256 + tid;
            int row = idx >> 3;
            int gc  = (idx & 7) ^ (row & 7);
            gload_lds16(B1 + (size_t)(n0 + row) * D_DIM + k0 + gc * 8,
                        &As[(idx & ~63) * 8]);
        }
        // stage Bs: 128 rows x 8 chunks = 1024 chunks, 4 rounds
        #pragma unroll
        for (int r = 0; r < 4; r++) {
            int idx = r * 256 + tid;
            int row = idx >> 3;
            int gc  = (idx & 7) ^ (row & 7);
            gload_lds16(B2 + (size_t)(m0 + row) * D_DIM + k0 + gc * 8,
                        &Bs[(idx & ~63) * 8]);
        }
        __syncthreads();

        #pragma unroll
        for (int kk = 0; kk < 2; kk++) {
            short8 a[8], b[4];
            #pragma unroll
            for (int ti = 0; ti < 8; ti++) {
                int row = n_off + ti * 16 + c;
                int ch  = (kk * 4 + quad) ^ (row & 7);
                a[ti] = *(const short8*)&As[row * BK + ch * 8];
            }
            #pragma unroll
            for (int tj = 0; tj < 4; tj++) {
                int row = m_off + tj * 16 + c;
                int ch  = (kk * 4 + quad) ^ (row & 7);
                b[tj] = *(const short8*)&Bs[row * BK + ch * 8];
            }
            #pragma unroll
            for (int ti = 0; ti < 8; ti++)
                #pragma unroll
                for (int tj = 0; tj < 4; tj++)
                    acc[ti][tj] = __builtin_amdgcn_mfma_f32_16x16x32_bf16(
                        a[ti], b[tj], acc[ti][tj], 0, 0, 0);
        }
        __syncthreads();
    }

    // epilogue: d2 = sq1[n]+sq2[m]-2*gram; C/D: col(m)=lane&15, row(n)=quad*4+reg
    float sqm[4];
    #pragma unroll
    for (int tj = 0; tj < 4; tj++) sqm[tj] = sq2[m0 + m_off + tj * 16 + c];
    float cmin[4];
    #pragma unroll
    for (int tj = 0; tj < 4; tj++) cmin[tj] = __uint_as_float(INF_BITS);

    #pragma unroll
    for (int ti = 0; ti < 8; ti++) {
        float4 sqn = *(const float4*)&sq1[n0 + n_off + ti * 16 + quad * 4];
        float rmin[4] = { __uint_as_float(INF_BITS), __uint_as_float(INF_BITS),
                          __uint_as_float(INF_BITS), __uint_as_float(INF_BITS) };
        #pragma unroll
        for (int tj = 0; tj < 4; tj++) {
            float sn[4] = { sqn.x, sqn.y, sqn.z, sqn.w };
            #pragma unroll
            for (int r = 0; r < 4; r++) {
                float d2 = fmaxf(sn[r] + sqm[tj] - 2.f * acc[ti][tj][r], 0.f);
                rmin[r]  = fminf(rmin[r], d2);
                cmin[tj] = fminf(cmin[tj], d2);
            }
        }
        // reduce row-mins over the 16 lanes (c) of the quad
        #pragma unroll
        for (int m = 1; m <= 8; m <<= 1)
            #pragma unroll
            for (int r = 0; r < 4; r++)
                rmin[r] = fminf(rmin[r], __shfl_xor(rmin[r], m, 64));
        if (c == 0) {
            #pragma unroll
            for (int r = 0; r < 4; r++)
                atomicMin(&rs[n_off + ti * 16 + quad * 4 + r], __float_as_uint(rmin[r]));
        }
    }
    // reduce col-mins over the 4 quads
    #pragma unroll
    for (int m = 16; m <= 32; m <<= 1)
        #pragma unroll
        for (int tj = 0; tj < 4; tj++)
            cmin[tj] = fminf(cmin[tj], __shfl_xor(cmin[tj], m, 64));
    if (quad == 0) {
        #pragma unroll
        for (int tj = 0; tj < 4; tj++)
            atomicMin(&cs[m_off + tj * 16 + c], __float_as_uint(cmin[tj]));
    }
    __syncthreads();

    atomicMin(&rowmin2[n0 + tid], rs[tid]);          // BN == 256 == blockDim
    if (tid < BM) atomicMin(&colmin2[m0 + tid], cs[tid]);

    // ---- last-block final reduction ----
    __threadfence();                                  // release our atomicMins
    __syncthreads();
    if (tid == 0) s_last = (atomicAdd(counter, 1) == NBLK - 1) ? 1u : 0u;
    __syncthreads();
    if (s_last) {
        __threadfence();                              // acquire
        const unsigned* mins = rowmin2;               // rowmin2+colmin2 contiguous: 16384 uints
        float s = 0.f;
        for (int base = 0; base < 2 * N_PTS; base += 2048) {
            unsigned v[8];
            #pragma unroll
            for (int j = 0; j < 8; j++)
                v[j] = __hip_atomic_load(&mins[base + j * 256 + tid],
                                         __ATOMIC_RELAXED, __HIP_MEMORY_SCOPE_AGENT);
            #pragma unroll
            for (int j = 0; j < 8; j++) s += sqrtf(__uint_as_float(v[j]));
        }
        #pragma unroll
        for (int off = 32; off > 0; off >>= 1) s += __shfl_down(s, off, 64);
        if (lane == 0) wsum[w] = s;
        __syncthreads();
        if (tid == 0) out[0] = (wsum[0] + wsum[1] + wsum[2] + wsum[3]) / (float)N_PTS;
    }
}

extern "C" void kernel_launch(void* const* d_in, const int* in_sizes, int n_in,
                              void* d_out, int out_size, void* d_ws, size_t ws_size,
                              hipStream_t stream) {
    const float* set1 = (const float*)d_in[0];
    const float* set2 = (const float*)d_in[1];
    float* out = (float*)d_out;

    // workspace: rowmin2[8192] | colmin2[8192] (contiguous!) | sq1 | sq2 | counter | b1 | b2
    unsigned* rowmin2 = (unsigned*)d_ws;
    unsigned* colmin2 = rowmin2 + N_PTS;
    float* sq1 = (float*)(colmin2 + N_PTS);
    float* sq2 = sq1 + N_PTS;
    unsigned* counter = (unsigned*)(sq2 + N_PTS);
    ushort* b1 = (ushort*)((char*)d_ws + 128 * 1024);       // 256B-aligned, past headers
    ushort* b2 = b1 + (size_t)N_PTS * D_DIM;

    prep_kernel<<<(2 * N_PTS * D_DIM) / (256 * 8), 256, 0, stream>>>(
        set1, set2, b1, b2, sq1, sq2, rowmin2, colmin2, counter);
    tile_kernel<<<dim3(N_PTS / BM, N_PTS / BN), 256, 0, stream>>>(
        b1, b2, sq1, sq2, rowmin2, colmin2, counter, out);
}

// Round 5
// 122.470 us; speedup vs baseline: 1.9490x; 1.9490x over previous
//
#include <hip/hip_runtime.h>

#define N_PTS 8192
#define D_DIM 256
#define BN 256              // set1 rows per block
#define BM 128              // set2 rows per block
#define BK 64
#define INF_BITS 0x7F800000u

typedef __attribute__((ext_vector_type(8))) short short8;
typedef __attribute__((ext_vector_type(4))) float f32x4;

// async global->LDS, 16B/lane; LDS dest = wave-uniform base + lane*16
__device__ __forceinline__ void gload_lds16(const ushort* g, ushort* l) {
    __builtin_amdgcn_global_load_lds(
        (const __attribute__((address_space(1))) void*)g,
        (__attribute__((address_space(3))) void*)l, 16, 0, 0);
}

__device__ __forceinline__ ushort f2bf(float x) {
    unsigned u = __float_as_uint(x);
    return (ushort)((u + 0x7FFFu + ((u >> 16) & 1u)) >> 16);  // RNE, no NaNs here
}

// ---- fused prep: bf16 convert + row sqnorms (fp32 exact) + INF init ----
__global__ void prep_kernel(const float* __restrict__ s1, const float* __restrict__ s2,
                            ushort* __restrict__ b1, ushort* __restrict__ b2,
                            float* __restrict__ sq1, float* __restrict__ sq2,
                            unsigned* __restrict__ rowmin2, unsigned* __restrict__ colmin2) {
    const int half = N_PTS * D_DIM;
    int t = blockIdx.x * 256 + threadIdx.x;
    int e = t * 8;
    bool first = e < half;
    const float* src = first ? s1 : s2;
    ushort* dst = first ? b1 : b2;
    int off = first ? e : e - half;
    float4 v0 = *(const float4*)(src + off);
    float4 v1 = *(const float4*)(src + off + 4);
    float s = v0.x * v0.x + v0.y * v0.y + v0.z * v0.z + v0.w * v0.w
            + v1.x * v1.x + v1.y * v1.y + v1.z * v1.z + v1.w * v1.w;
    ushort4 o0 = { f2bf(v0.x), f2bf(v0.y), f2bf(v0.z), f2bf(v0.w) };
    ushort4 o1 = { f2bf(v1.x), f2bf(v1.y), f2bf(v1.z), f2bf(v1.w) };
    *(ushort4*)(dst + off)     = o0;
    *(ushort4*)(dst + off + 4) = o1;
    // one row = 32 consecutive threads; xor masks <=16 stay inside the half-wave
    #pragma unroll
    for (int m = 1; m <= 16; m <<= 1) s += __shfl_xor(s, m, 64);
    int sub = threadIdx.x & 31;
    int row = off >> 8;
    if (sub == 0) (first ? sq1 : sq2)[row] = s;
    if (sub == 1) (first ? rowmin2 : colmin2)[row] = INF_BITS;
}

// ---- MFMA gram + fused d^2 + row/col min ----
__global__ __launch_bounds__(256, 2) void tile_kernel(
    const ushort* __restrict__ B1, const ushort* __restrict__ B2,
    const float* __restrict__ sq1, const float* __restrict__ sq2,
    unsigned* __restrict__ rowmin2, unsigned* __restrict__ colmin2) {
    // unpadded row-major [rows][BK] bf16, XOR-swizzled in 16B chunks:
    // LDS slot (row, sc) holds global chunk (row, sc ^ (row&7))
    __shared__ ushort As[BN * BK] __attribute__((aligned(16)));   // 32 KB
    __shared__ ushort Bs[BM * BK] __attribute__((aligned(16)));   // 16 KB
    __shared__ unsigned rs[BN];
    __shared__ unsigned cs[BM];

    const int tid  = threadIdx.x;
    const int lane = tid & 63;
    const int w    = tid >> 6;
    const int quad = lane >> 4;
    const int c    = lane & 15;
    const int n_off = (w >> 1) * 128;   // wave tile: 128(n) x 64(m)
    const int m_off = (w & 1) * 64;
    const int n0 = blockIdx.y * BN;
    const int m0 = blockIdx.x * BM;

    rs[tid] = INF_BITS;
    if (tid < BM) cs[tid] = INF_BITS;

    f32x4 acc[8][4];
    #pragma unroll
    for (int ti = 0; ti < 8; ti++)
        #pragma unroll
        for (int tj = 0; tj < 4; tj++) acc[ti][tj] = (f32x4){0.f, 0.f, 0.f, 0.f};

    for (int k0 = 0; k0 < D_DIM; k0 += BK) {
        // stage As: 256 rows x 8 chunks = 2048 chunks, 8 rounds of 256
        #pragma unroll
        for (int r = 0; r < 8; r++) {
            int idx = r * 256 + tid;
            int row = idx >> 3;
            int gc  = (idx & 7) ^ (row & 7);
            gload_lds16(B1 + (size_t)(n0 + row) * D_DIM + k0 + gc * 8,
                        &As[(idx & ~63) * 8]);
        }
        // stage Bs: 128 rows x 8 chunks = 1024 chunks, 4 rounds
        #pragma unroll
        for (int r = 0; r < 4; r++) {
            int idx = r * 256 + tid;
            int row = idx >> 3;
            int gc  = (idx & 7) ^ (row & 7);
            gload_lds16(B2 + (size_t)(m0 + row) * D_DIM + k0 + gc * 8,
                        &Bs[(idx & ~63) * 8]);
        }
        __syncthreads();

        #pragma unroll
        for (int kk = 0; kk < 2; kk++) {
            short8 a[8], b[4];
            #pragma unroll
            for (int ti = 0; ti < 8; ti++) {
                int row = n_off + ti * 16 + c;
                int ch  = (kk * 4 + quad) ^ (row & 7);
                a[ti] = *(const short8*)&As[row * BK + ch * 8];
            }
            #pragma unroll
            for (int tj = 0; tj < 4; tj++) {
                int row = m_off + tj * 16 + c;
                int ch  = (kk * 4 + quad) ^ (row & 7);
                b[tj] = *(const short8*)&Bs[row * BK + ch * 8];
            }
            #pragma unroll
            for (int ti = 0; ti < 8; ti++)
                #pragma unroll
                for (int tj = 0; tj < 4; tj++)
                    acc[ti][tj] = __builtin_amdgcn_mfma_f32_16x16x32_bf16(
                        a[ti], b[tj], acc[ti][tj], 0, 0, 0);
        }
        __syncthreads();
    }

    // epilogue: d2 = sq1[n]+sq2[m]-2*gram; C/D: col(m)=lane&15, row(n)=quad*4+reg
    float sqm[4];
    #pragma unroll
    for (int tj = 0; tj < 4; tj++) sqm[tj] = sq2[m0 + m_off + tj * 16 + c];
    float cmin[4];
    #pragma unroll
    for (int tj = 0; tj < 4; tj++) cmin[tj] = __uint_as_float(INF_BITS);

    #pragma unroll
    for (int ti = 0; ti < 8; ti++) {
        float4 sqn = *(const float4*)&sq1[n0 + n_off + ti * 16 + quad * 4];
        float rmin[4] = { __uint_as_float(INF_BITS), __uint_as_float(INF_BITS),
                          __uint_as_float(INF_BITS), __uint_as_float(INF_BITS) };
        #pragma unroll
        for (int tj = 0; tj < 4; tj++) {
            float sn[4] = { sqn.x, sqn.y, sqn.z, sqn.w };
            #pragma unroll
            for (int r = 0; r < 4; r++) {
                float d2 = fmaxf(sn[r] + sqm[tj] - 2.f * acc[ti][tj][r], 0.f);
                rmin[r]  = fminf(rmin[r], d2);
                cmin[tj] = fminf(cmin[tj], d2);
            }
        }
        // reduce row-mins over the 16 lanes (c) of the quad
        #pragma unroll
        for (int m = 1; m <= 8; m <<= 1)
            #pragma unroll
            for (int r = 0; r < 4; r++)
                rmin[r] = fminf(rmin[r], __shfl_xor(rmin[r], m, 64));
        if (c == 0) {
            #pragma unroll
            for (int r = 0; r < 4; r++)
                atomicMin(&rs[n_off + ti * 16 + quad * 4 + r], __float_as_uint(rmin[r]));
        }
    }
    // reduce col-mins over the 4 quads
    #pragma unroll
    for (int m = 16; m <= 32; m <<= 1)
        #pragma unroll
        for (int tj = 0; tj < 4; tj++)
            cmin[tj] = fminf(cmin[tj], __shfl_xor(cmin[tj], m, 64));
    if (quad == 0) {
        #pragma unroll
        for (int tj = 0; tj < 4; tj++)
            atomicMin(&cs[m_off + tj * 16 + c], __float_as_uint(cmin[tj]));
    }
    __syncthreads();

    atomicMin(&rowmin2[n0 + tid], rs[tid]);          // BN == 256 == blockDim
    if (tid < BM) atomicMin(&colmin2[m0 + tid], cs[tid]);
}

// ---- final: mean(sqrt(min d^2)) over rowmin2||colmin2 (contiguous 2*N_PTS) ----
__global__ __launch_bounds__(1024) void reduce_kernel(const unsigned* __restrict__ mins,
                                                      float* __restrict__ out) {
    int tid = threadIdx.x;
    uint4 v[4];
    #pragma unroll
    for (int j = 0; j < 4; j++) v[j] = ((const uint4*)mins)[j * 1024 + tid];
    float s = 0.f;
    #pragma unroll
    for (int j = 0; j < 4; j++)
        s += sqrtf(__uint_as_float(v[j].x)) + sqrtf(__uint_as_float(v[j].y))
           + sqrtf(__uint_as_float(v[j].z)) + sqrtf(__uint_as_float(v[j].w));
    #pragma unroll
    for (int m = 32; m > 0; m >>= 1) s += __shfl_xor(s, m, 64);
    __shared__ float ws[16];
    int lane = tid & 63, wv = tid >> 6;
    if (lane == 0) ws[wv] = s;
    __syncthreads();
    if (tid < 16) {
        float t = ws[tid];
        #pragma unroll
        for (int m = 8; m > 0; m >>= 1) t += __shfl_xor(t, m, 64);
        if (tid == 0) out[0] = t / (float)N_PTS;
    }
}

extern "C" void kernel_launch(void* const* d_in, const int* in_sizes, int n_in,
                              void* d_out, int out_size, void* d_ws, size_t ws_size,
                              hipStream_t stream) {
    const float* set1 = (const float*)d_in[0];
    const float* set2 = (const float*)d_in[1];
    float* out = (float*)d_out;

    // workspace: rowmin2[8192] | colmin2[8192] (contiguous!) | sq1 | sq2 | pad | b1 | b2
    unsigned* rowmin2 = (unsigned*)d_ws;
    unsigned* colmin2 = rowmin2 + N_PTS;
    float* sq1 = (float*)(colmin2 + N_PTS);
    float* sq2 = sq1 + N_PTS;
    ushort* b1 = (ushort*)((char*)d_ws + 128 * 1024);       // 256B-aligned, past headers
    ushort* b2 = b1 + (size_t)N_PTS * D_DIM;

    prep_kernel<<<(2 * N_PTS * D_DIM) / (256 * 8), 256, 0, stream>>>(
        set1, set2, b1, b2, sq1, sq2, rowmin2, colmin2);
    tile_kernel<<<dim3(N_PTS / BM, N_PTS / BN), 256, 0, stream>>>(
        b1, b2, sq1, sq2, rowmin2, colmin2);
    reduce_kernel<<<1, 1024, 0, stream>>>(rowmin2, out);
}